// Round 13
// baseline (269.845 us; speedup 1.0000x reference)
//
#include <hip/hip_runtime.h>
#include <hip/hip_bf16.h>

// Bahdanau attention, B=32 S=2048 H=1024, fp32 in/out.
// v13: k_scores13 = full 256^2 8-wave 4-phase-per-K-tile template (m198/m201
// family): BM=BN=256, BK=64, dbuf 132 KB dynamic LDS, per phase
// {12 ds_read + 2 gload16 -> sched_barrier -> s_barrier -> 16 MFMA ->
//  s_barrier}, __syncthreads (vmcnt0 drain) only at K-tile boundary.
// v5's proven 8-slot swizzle. 4 o-tiles -> softmax sums 4 partials.
// Fallback v1 fused path if ws too small.

#define BB 32
#define SS 2048
#define HH 1024

typedef float  f32x4  __attribute__((ext_vector_type(4)));
typedef __bf16 bf16x4 __attribute__((ext_vector_type(4)));
typedef __bf16 bf16x8 __attribute__((ext_vector_type(8)));

__device__ inline __bf16 f2bf(float f) {
  unsigned u = __builtin_bit_cast(unsigned, f);
  u = (u + 0x7FFFu + ((u >> 16) & 1u)) >> 16;   // RNE (inputs are finite)
  unsigned short s = (unsigned short)u;
  return __builtin_bit_cast(__bf16, s);
}

__device__ inline float bf2f(__bf16 b) {
  unsigned short s = __builtin_bit_cast(unsigned short, b);
  unsigned u = ((unsigned)s) << 16;
  return __builtin_bit_cast(float, u);
}

__device__ inline float tanh_fast(float x) {
  x = fminf(fmaxf(x, -15.f), 15.f);
  float e = __expf(2.f * x);
  return (e - 1.f) / (e + 1.f);
}

__device__ __forceinline__ void gload16(const __bf16* g, __bf16* l) {
  __builtin_amdgcn_global_load_lds(
      (const __attribute__((address_space(1))) void*)g,
      (__attribute__((address_space(3))) void*)l, 16, 0, 0);
}

// ---- keys f32 -> bf16 (row-major) ----
__global__ void k_convert_keys(const float* __restrict__ src, __bf16* __restrict__ dst) {
  size_t i = ((size_t)blockIdx.x * 256 + threadIdx.x) * 8;
  f32x4 a = *(const f32x4*)(src + i);
  f32x4 b = *(const f32x4*)(src + i + 4);
  bf16x8 o;
  o[0] = f2bf(a[0]); o[1] = f2bf(a[1]); o[2] = f2bf(a[2]); o[3] = f2bf(a[3]);
  o[4] = f2bf(b[0]); o[5] = f2bf(b[1]); o[6] = f2bf(b[2]); o[7] = f2bf(b[3]);
  *(bf16x8*)(dst + i) = o;
}

// ---- Ua f32 -> bf16 (row-major) ----
__global__ void k_convert_ua(const float* __restrict__ src, __bf16* __restrict__ dst) {
  size_t i = (size_t)blockIdx.x * 256 + threadIdx.x;   // x4 elements
  f32x4 v = ((const f32x4*)src)[i];
  bf16x4 o;
  o[0] = f2bf(v[0]); o[1] = f2bf(v[1]); o[2] = f2bf(v[2]); o[3] = f2bf(v[3]);
  *(bf16x4*)(dst + i * 4) = o;
}

// ---- qpc[b][o] = dot(query[b], Wa[o]) + Wa_b[o] + Ua_b[o] ----
__global__ void k_qproj(const float* __restrict__ q, const float* __restrict__ wa,
                        const float* __restrict__ wab, const float* __restrict__ uab,
                        float* __restrict__ qpc) {
  int tid = threadIdx.x;
  int gid = blockIdx.x * 32 + (tid >> 3);
  int lane8 = tid & 7;
  int b = gid >> 10, o = gid & 1023;
  const f32x4* qv = (const f32x4*)(q + (size_t)b * HH);
  const f32x4* wv = (const f32x4*)(wa + (size_t)o * HH);
  float s = 0.f;
#pragma unroll 4
  for (int kk = lane8; kk < HH / 4; kk += 8) {
    f32x4 a = qv[kk], w = wv[kk];
    s += a[0] * w[0] + a[1] * w[1] + a[2] * w[2] + a[3] * w[3];
  }
  s += __shfl_xor(s, 1); s += __shfl_xor(s, 2); s += __shfl_xor(s, 4);
  if (lane8 == 0) qpc[(size_t)b * HH + o] = s + wab[o] + uab[o];
}

// ---- 256^2 8-wave fused GEMM + tanh + Va -> per-o-tile score partials ----
// grid 1024 = 256 m-tiles x 4 o-tiles; bijective XCD swizzle keeps the 4
// o-tiles of an m-tile (and 1/8 of m-tiles) on one XCD.
// LDS (dynamic 132 KB): A dbuf 2x32K, B dbuf 2x32K, scorebuf 4K.
// Swizzle (v5): LDS 16B-slot s of row r holds global k-octet (s-r)&7.
__global__ void __launch_bounds__(512, 2) k_scores13(
    const __bf16* __restrict__ keysb, const __bf16* __restrict__ ua,
    const float* __restrict__ qpc, const float* __restrict__ vaw,
    float* __restrict__ spart) {
  extern __shared__ __align__(16) __bf16 smem[];
  __bf16* Ab0 = smem;                          // [2][256*64]
  __bf16* Bb0 = smem + 2 * 16384;              // [2][256*64]
  float* scorebuf = (float*)(smem + 4 * 16384);  // [256][4]

  int raw = blockIdx.x;
  int o = (raw >> 3) & 3;
  int m = ((raw >> 5) << 3) | (raw & 7);
  int b = m >> 3;                        // 8 m-tiles per batch
  long grow0 = (long)m * 256;
  int o0 = o * 256;

  int tid = threadIdx.x;
  int w = tid >> 6, lane = tid & 63;
  int wm = w >> 2, wn = w & 3;           // 2 x 4 waves; per-wave 128x64 out
  int ln = lane & 15, hi = lane >> 4;

  // staging: 64 rows/instr; thread -> row (tid>>3), LDS slot tid&7,
  // global k-octet (slot - row)&7 (row mod 8 invariant across half-tiles)
  int srow = tid >> 3;
  int sslot = tid & 7;
  int g = (sslot - srow) & 7;
  const __bf16* asrc = keysb + (size_t)(grow0 + srow) * HH + g * 8;
  const __bf16* bsrc = ua + (size_t)(o0 + srow) * HH + g * 8;
  int wrofs = (w * 8) * 64;              // wave-uniform dest row offset

#define STG(SRC, DSTB, H, I, KO, BOFS)                                        \
  gload16((SRC) + (size_t)((H)*128 + (I)*64) * HH + (KO),                     \
          (DSTB) + (BOFS) + ((H)*128 + (I)*64) * 64 + wrofs)

  // fragment read slot offsets (v5 swizzle): k-octet g=kk*4+hi, row%8==ln%8
  int sa0 = ((hi + ln) & 7) * 8;         // kk=0
  int sa1 = ((4 + hi + ln) & 7) * 8;     // kk=1

  f32x4 acc[8][4] = {};

  // prologue: tile 0 -> buf 0 (4 half-tiles), full drain
  STG(asrc, Ab0, 0, 0, 0, 0); STG(asrc, Ab0, 0, 1, 0, 0);
  STG(asrc, Ab0, 1, 0, 0, 0); STG(asrc, Ab0, 1, 1, 0, 0);
  STG(bsrc, Bb0, 0, 0, 0, 0); STG(bsrc, Bb0, 0, 1, 0, 0);
  STG(bsrc, Bb0, 1, 0, 0, 0); STG(bsrc, Bb0, 1, 1, 0, 0);
  __syncthreads();

  for (int t = 0; t < 16; ++t) {         // K = 1024, BK = 64
    int cb = (t & 1) * 16384;            // compute buffer
    int sb = 16384 - cb;                 // stage buffer (tile t+1)
    int kn = (t + 1 < 16 ? t + 1 : 15) * 64;  // tail re-stages tile 15 (safe)
    const __bf16* A = Ab0 + cb;
    const __bf16* B = Bb0 + cb;
#pragma unroll
    for (int p = 0; p < 4; ++p) {        // phase = C-quadrant (mq, nq)
      const int mq = p >> 1, nq = p & 1;
      bf16x8 af[4][2], bfr[2][2];
#pragma unroll
      for (int mi2 = 0; mi2 < 4; ++mi2) {
        int r = (wm * 128 + mq * 64 + mi2 * 16 + ln) * 64;
        af[mi2][0] = *(const bf16x8*)(A + r + sa0);
        af[mi2][1] = *(const bf16x8*)(A + r + sa1);
      }
#pragma unroll
      for (int ni2 = 0; ni2 < 2; ++ni2) {
        int r = (wn * 64 + nq * 32 + ni2 * 16 + ln) * 64;
        bfr[ni2][0] = *(const bf16x8*)(B + r + sa0);
        bfr[ni2][1] = *(const bf16x8*)(B + r + sa1);
      }
      // stage one half-tile of tile t+1
      if (p == 0)      { STG(asrc, Ab0, 0, 0, kn, sb); STG(asrc, Ab0, 0, 1, kn, sb); }
      else if (p == 1) { STG(asrc, Ab0, 1, 0, kn, sb); STG(asrc, Ab0, 1, 1, kn, sb); }
      else if (p == 2) { STG(bsrc, Bb0, 0, 0, kn, sb); STG(bsrc, Bb0, 0, 1, kn, sb); }
      else             { STG(bsrc, Bb0, 1, 0, kn, sb); STG(bsrc, Bb0, 1, 1, kn, sb); }
      __builtin_amdgcn_sched_barrier(0); // loads pinned before the barrier
      __builtin_amdgcn_s_barrier();
      __builtin_amdgcn_s_setprio(1);
#pragma unroll
      for (int kk = 0; kk < 2; ++kk)
#pragma unroll
        for (int mi2 = 0; mi2 < 4; ++mi2)
#pragma unroll
          for (int ni2 = 0; ni2 < 2; ++ni2)
            acc[mq * 4 + mi2][nq * 2 + ni2] = __builtin_amdgcn_mfma_f32_16x16x32_bf16(
                af[mi2][kk], bfr[ni2][kk], acc[mq * 4 + mi2][nq * 2 + ni2], 0, 0, 0);
      __builtin_amdgcn_s_setprio(0);
      if (p < 3) __builtin_amdgcn_s_barrier();
    }
    __syncthreads();                     // tile boundary: full drain + barrier
  }
#undef STG

  // epilogue: rowsum of tanh(kp+qpc)*va over this wave's 64 cols, then
  // cross-wave (4 wn) reduce in LDS -> spart[o][grow0 + r]
  float qv[4], vv[4];
#pragma unroll
  for (int ni = 0; ni < 4; ++ni) {
    int oc = o0 + wn * 64 + ni * 16 + ln;
    qv[ni] = qpc[(size_t)b * HH + oc];
    vv[ni] = vaw[oc];
  }
#pragma unroll
  for (int mi = 0; mi < 8; ++mi)
#pragma unroll
    for (int j = 0; j < 4; ++j) {
      float v = 0.f;
#pragma unroll
      for (int ni = 0; ni < 4; ++ni)
        v += tanh_fast(acc[mi][ni][j] + qv[ni]) * vv[ni];
      v += __shfl_xor(v, 1); v += __shfl_xor(v, 2);
      v += __shfl_xor(v, 4); v += __shfl_xor(v, 8);   // sum over 16 cols (ln)
      if (ln == 0)
        scorebuf[(wm * 128 + mi * 16 + hi * 4 + j) * 4 + wn] = v;
    }
  __syncthreads();
  if (tid < 256) {
    float s = (scorebuf[tid * 4 + 0] + scorebuf[tid * 4 + 1]) +
              (scorebuf[tid * 4 + 2] + scorebuf[tid * 4 + 3]);
    spart[(size_t)o * (BB * SS) + grow0 + tid] = s;
  }
}

// ---- softmax over S per batch, 4 o-partials (Va_b cancels) ----
__global__ void k_softmax4(const float* __restrict__ spart, float* __restrict__ wout) {
  int b = blockIdx.x, tid = threadIdx.x;
  __shared__ float red[8];
  int w = tid >> 6;
  float sc[8];
  float mx = -1e30f;
#pragma unroll
  for (int i = 0; i < 8; ++i) {
    int s = tid + i * 256;
    float v = 0.f;
#pragma unroll
    for (int ot = 0; ot < 4; ++ot) v += spart[(size_t)ot * (BB * SS) + b * SS + s];
    sc[i] = v; mx = fmaxf(mx, v);
  }
#pragma unroll
  for (int off = 1; off < 64; off <<= 1) mx = fmaxf(mx, __shfl_xor(mx, off));
  if ((tid & 63) == 0) red[w] = mx;
  __syncthreads();
  mx = fmaxf(fmaxf(red[0], red[1]), fmaxf(red[2], red[3]));
  float sum = 0.f;
#pragma unroll
  for (int i = 0; i < 8; ++i) { sc[i] = __expf(sc[i] - mx); sum += sc[i]; }
#pragma unroll
  for (int off = 1; off < 64; off <<= 1) sum += __shfl_xor(sum, off);
  if ((tid & 63) == 0) red[4 + w] = sum;
  __syncthreads();
  sum = (red[4] + red[5]) + (red[6] + red[7]);
  float inv = 1.f / sum;
#pragma unroll
  for (int i = 0; i < 8; ++i) wout[(size_t)b * SS + tid + i * 256] = sc[i] * inv;
}

// ---- softmax over S per batch, 8 o-partials (fallback path) ----
__global__ void k_softmax(const float* __restrict__ spart, float* __restrict__ wout) {
  int b = blockIdx.x, tid = threadIdx.x;
  __shared__ float red[8];
  int w = tid >> 6;
  float sc[8];
  float mx = -1e30f;
#pragma unroll
  for (int i = 0; i < 8; ++i) {
    int s = tid + i * 256;
    float v = 0.f;
#pragma unroll
    for (int ot = 0; ot < 8; ++ot) v += spart[(size_t)ot * (BB * SS) + b * SS + s];
    sc[i] = v; mx = fmaxf(mx, v);
  }
#pragma unroll
  for (int off = 1; off < 64; off <<= 1) mx = fmaxf(mx, __shfl_xor(mx, off));
  if ((tid & 63) == 0) red[w] = mx;
  __syncthreads();
  mx = fmaxf(fmaxf(red[0], red[1]), fmaxf(red[2], red[3]));
  float sum = 0.f;
#pragma unroll
  for (int i = 0; i < 8; ++i) { sc[i] = __expf(sc[i] - mx); sum += sc[i]; }
#pragma unroll
  for (int off = 1; off < 64; off <<= 1) sum += __shfl_xor(sum, off);
  if ((tid & 63) == 0) red[4 + w] = sum;
  __syncthreads();
  sum = (red[4] + red[5]) + (red[6] + red[7]);
  float inv = 1.f / sum;
#pragma unroll
  for (int i = 0; i < 8; ++i) wout[(size_t)b * SS + tid + i * 256] = sc[i] * inv;
}

// ---- v1 fused-conversion GEMM (fallback when ws is small) ----
__global__ void __launch_bounds__(256) k_scores_fused(
    const float* __restrict__ keys, const __bf16* __restrict__ ua,
    const float* __restrict__ qpc, const float* __restrict__ vaw,
    float* __restrict__ spart) {
  __shared__ __bf16 Alds[128][40];
  __shared__ float scorebuf[128];

  int raw = blockIdx.x;
  int o = (raw >> 3) & 7;
  int m = ((raw >> 6) << 3) | (raw & 7);
  int b = m >> 4;
  long grow0 = (long)m * 128;
  int o0 = o * 128;

  int tid = threadIdx.x;
  int w = tid >> 6, lane = tid & 63;
  int wm = w >> 1, wn = w & 1;
  int ln = lane & 15, hi = lane >> 4;

  int srow = tid >> 3;
  int sk4 = tid & 7;
  const f32x4* keysv = (const f32x4*)keys;
  const bf16x8* uav = (const bf16x8*)ua;

  f32x4 acc[4][4] = {};

  for (int kt = 0; kt < 32; ++kt) {
    int k0 = kt * 32;
    bf16x8 bf[4];
#pragma unroll
    for (int ni = 0; ni < 4; ++ni) {
      int oc = o0 + wn * 64 + ni * 16 + ln;
      bf[ni] = uav[(size_t)oc * (HH / 8) + (k0 >> 3) + hi];
    }
    f32x4 st[4];
#pragma unroll
    for (int p = 0; p < 4; ++p)
      st[p] = keysv[((size_t)(grow0 + srow + 32 * p) << 8) + (size_t)(kt * 8 + sk4)];
    __syncthreads();
#pragma unroll
    for (int p = 0; p < 4; ++p) {
      bf16x4 t;
      t[0] = f2bf(st[p][0]); t[1] = f2bf(st[p][1]);
      t[2] = f2bf(st[p][2]); t[3] = f2bf(st[p][3]);
      *(bf16x4*)&Alds[srow + 32 * p][sk4 * 4] = t;
    }
    __syncthreads();
    bf16x8 af[4];
#pragma unroll
    for (int mi = 0; mi < 4; ++mi)
      af[mi] = *(const bf16x8*)&Alds[wm * 64 + mi * 16 + ln][hi * 8];
#pragma unroll
    for (int mi = 0; mi < 4; ++mi)
#pragma unroll
      for (int ni = 0; ni < 4; ++ni)
        acc[mi][ni] = __builtin_amdgcn_mfma_f32_16x16x32_bf16(af[mi], bf[ni], acc[mi][ni], 0, 0, 0);
  }

  float qv[4], vv[4];
#pragma unroll
  for (int ni = 0; ni < 4; ++ni) {
    int oc = o0 + wn * 64 + ni * 16 + ln;
    qv[ni] = qpc[(size_t)b * HH + oc];
    vv[ni] = vaw[oc];
  }
  float rsum[4][4];
#pragma unroll
  for (int mi = 0; mi < 4; ++mi)
#pragma unroll
    for (int j = 0; j < 4; ++j) {
      float v = 0.f;
#pragma unroll
      for (int ni = 0; ni < 4; ++ni)
        v += tanh_fast(acc[mi][ni][j] + qv[ni]) * vv[ni];
      v += __shfl_xor(v, 1); v += __shfl_xor(v, 2);
      v += __shfl_xor(v, 4); v += __shfl_xor(v, 8);
      rsum[mi][j] = v;
    }
  if (wn == 1 && ln == 0) {
#pragma unroll
    for (int mi = 0; mi < 4; ++mi)
#pragma unroll
      for (int j = 0; j < 4; ++j)
        scorebuf[wm * 64 + mi * 16 + hi * 4 + j] = rsum[mi][j];
  }
  __syncthreads();
  if (wn == 0 && ln == 0) {
#pragma unroll
    for (int mi = 0; mi < 4; ++mi)
#pragma unroll
      for (int j = 0; j < 4; ++j) {
        int rl = wm * 64 + mi * 16 + hi * 4 + j;
        spart[(size_t)o * (BB * SS) + grow0 + rl] = rsum[mi][j] + scorebuf[rl];
      }
  }
}

// ---- context partials from bf16 keys: 512 blocks = 32 b x 16 s-chunks ----
__global__ void k_ctx_part_bf(const __bf16* __restrict__ keysb, const float* __restrict__ wts,
                              float* __restrict__ cpart) {
  int bc = blockIdx.x;
  int b = bc >> 4, sc = bc & 15;
  int tid = threadIdx.x;
  int s0 = sc * 128;
  f32x4 a0 = {0,0,0,0}, a1 = {0,0,0,0}, a2 = {0,0,0,0}, a3 = {0,0,0,0};
  for (int s = 0; s < 128; s += 4) {
    size_t base = (size_t)b * SS + s0 + s;
    float w0 = wts[base + 0], w1 = wts[base + 1], w2 = wts[base + 2], w3 = wts[base + 3];
    bf16x4 k0 = *(const bf16x4*)(keysb + (base + 0) * HH + tid * 4);
    bf16x4 k1 = *(const bf16x4*)(keysb + (base + 1) * HH + tid * 4);
    bf16x4 k2 = *(const bf16x4*)(keysb + (base + 2) * HH + tid * 4);
    bf16x4 k3 = *(const bf16x4*)(keysb + (base + 3) * HH + tid * 4);
#pragma unroll
    for (int j = 0; j < 4; ++j) {
      a0[j] += w0 * bf2f(k0[j]);
      a1[j] += w1 * bf2f(k1[j]);
      a2[j] += w2 * bf2f(k2[j]);
      a3[j] += w3 * bf2f(k3[j]);
    }
  }
  f32x4 a = (a0 + a1) + (a2 + a3);
  ((f32x4*)cpart)[(size_t)bc * (HH / 4) + tid] = a;
}

// ---- fp32-keys context partial (fallback path) ----
__global__ void k_ctx_part(const float* __restrict__ keys, const float* __restrict__ wts,
                           float* __restrict__ cpart) {
  int bc = blockIdx.x;
  int b = bc >> 4, sc = bc & 15;
  int tid = threadIdx.x;
  int s0 = sc * 128;
  const f32x4* kv = (const f32x4*)keys;
  f32x4 a0 = {0,0,0,0}, a1 = {0,0,0,0}, a2 = {0,0,0,0}, a3 = {0,0,0,0};
  for (int s = 0; s < 128; s += 4) {
    size_t base = (size_t)b * SS + s0 + s;
    a0 += wts[base + 0] * kv[(base + 0) * (HH / 4) + tid];
    a1 += wts[base + 1] * kv[(base + 1) * (HH / 4) + tid];
    a2 += wts[base + 2] * kv[(base + 2) * (HH / 4) + tid];
    a3 += wts[base + 3] * kv[(base + 3) * (HH / 4) + tid];
  }
  f32x4 a = (a0 + a1) + (a2 + a3);
  ((f32x4*)cpart)[(size_t)bc * (HH / 4) + tid] = a;
}

__global__ void k_ctx_red(const float* __restrict__ cpart, float* __restrict__ ctx) {
  int i = blockIdx.x * 256 + threadIdx.x;  // over B*H
  int b = i >> 10, h = i & 1023;
  float v = 0.f;
#pragma unroll
  for (int sc = 0; sc < 16; ++sc) v += cpart[((size_t)(b * 16 + sc)) * HH + h];
  ctx[i] = v;
}

extern "C" void kernel_launch(void* const* d_in, const int* in_sizes, int n_in,
                              void* d_out, int out_size, void* d_ws, size_t ws_size,
                              hipStream_t stream) {
  (void)in_sizes; (void)n_in; (void)out_size;
  const float* query = (const float*)d_in[0];
  const float* keys  = (const float*)d_in[1];
  const float* wa_w  = (const float*)d_in[2];
  const float* wa_b  = (const float*)d_in[3];
  const float* ua_w  = (const float*)d_in[4];
  const float* ua_b  = (const float*)d_in[5];
  const float* va_w  = (const float*)d_in[6];
  // va_b (d_in[7]) cancels in softmax

  char* ws = (char*)d_ws;
  float* ctx_out = (float*)d_out;            // [32][1024]
  float* w_out   = ctx_out + BB * HH;        // [32][2048]

  const size_t need = (size_t)135 << 20;
  if (ws_size >= need) {
    __bf16* keys_bf = (__bf16*)ws;                              // 128 MB
    __bf16* ua_bf   = (__bf16*)(ws + ((size_t)128 << 20));      // 2 MB
    float*  qpc     = (float*)(ws + ((size_t)130 << 20));       // 128 KB
    float*  spart   = (float*)(ws + ((size_t)131 << 20));       // 1 MB (4 slices)
    float*  cpart   = (float*)(ws + ((size_t)133 << 20));       // 2 MB

    const int lds_bytes = 135168;  // 132 KB dynamic LDS
    (void)hipFuncSetAttribute((const void*)k_scores13,
                              hipFuncAttributeMaxDynamicSharedMemorySize, lds_bytes);

    k_convert_keys<<<BB * SS * HH / (256 * 8), 256, 0, stream>>>(keys, keys_bf);
    k_convert_ua<<<1024, 256, 0, stream>>>(ua_w, ua_bf);
    k_qproj<<<1024, 256, 0, stream>>>(query, wa_w, wa_b, ua_b, qpc);
    k_scores13<<<1024, 512, lds_bytes, stream>>>(keys_bf, ua_bf, qpc, va_w, spart);
    k_softmax4<<<BB, 256, 0, stream>>>(spart, w_out);
    k_ctx_part_bf<<<512, 256, 0, stream>>>(keys_bf, w_out, cpart);
    k_ctx_red<<<BB * HH / 256, 256, 0, stream>>>(cpart, ctx_out);
  } else {
    __bf16* ua_bf  = (__bf16*)ws;                                    // 2 MB
    float*  qpc    = (float*)(ws + (2u << 20));                      // 128 KB
    float*  spart  = (float*)(ws + (2u << 20) + (128u << 10));       // 2 MB
    float*  cpart  = (float*)(ws + (4u << 20) + (128u << 10));       // 2 MB

    k_convert_ua<<<1024, 256, 0, stream>>>(ua_w, ua_bf);
    k_qproj<<<1024, 256, 0, stream>>>(query, wa_w, wa_b, ua_b, qpc);
    k_scores_fused<<<4096, 256, 0, stream>>>(keys, ua_bf, qpc, va_w, spart);
    k_softmax<<<BB, 256, 0, stream>>>(spart, w_out);
    k_ctx_part<<<512, 256, 0, stream>>>(keys, w_out, cpart);
    k_ctx_red<<<BB * HH / 256, 256, 0, stream>>>(cpart, ctx_out);
  }
}